// Round 11
// baseline (162.623 us; speedup 1.0000x reference)
//
#include <hip/hip_runtime.h>

// Problem constants (fixed by setup_inputs)
#define NNODES 27648
#define NEDGES 442368
#define FIN    256
#define HC     512
#define NH     4
#define CDIM   128
#define NAG    48
#define NGRP   12
#define N2     2304    // 48*48
#define NOUT   576     // 12*48
#define CAP    128     // max edges kept per output row (Poisson mean ~16)
#define EDIM   16
#define MPART  512     // meansum partial blocks
#define PRE_WB 9                      // weight-precompute blocks
#define PRE_EB (PRE_WB + MPART)       // 521: first binning block
#define PREB   (PRE_EB + NEDGES/256)  // k_pre grid

// R11: eliminate k_scan. (a) easum via atomicAdd from k_pre's sum blocks;
// (b) binning absorbed into k_pre (stores EDGE INDEX; no we_ dependency;
// counts zeroed by a tiny memset); (c) src-resolve + aed=ea@we moved to a
// PARALLEL prologue in k_attn (one round of scattered loads by ~k threads,
// results in LDS — unlike R9, which chained them inside the serial per-wave
// logit loop). Attn logit loop now reads srcs/aed from LDS. Gemm tail and
// attn body otherwise byte-identical to R10 (best: 147.3 us).

__device__ __forceinline__ float lrelu(float v, float s){ return v > 0.0f ? v : s * v; }

__device__ __forceinline__ float wsum(float v){
  #pragma unroll
  for (int off = 32; off; off >>= 1) v += __shfl_xor(v, off, 64);
  return v;
}
__device__ __forceinline__ float wmax(float v){
  #pragma unroll
  for (int off = 32; off; off >>= 1) v = fmaxf(v, __shfl_xor(v, off, 64));
  return v;
}

// K1 (k_pre): blocks 0..8      ws/wd/we precompute
//             blocks 9..520    edge_attr column sums -> atomicAdd easum
//             blocks 521..     bin diagonal-dst edges (slist = edge index)
__global__ __launch_bounds__(256) void k_pre(
    const float* __restrict__ W, const float* __restrict__ att_src,
    const float* __restrict__ att_dst, const float* __restrict__ W_edge,
    const float* __restrict__ att_edge, const float* __restrict__ ea,
    const int* __restrict__ ei,
    float* __restrict__ ws_, float* __restrict__ wd_, float* __restrict__ we_,
    float* __restrict__ easum, int* __restrict__ counts, int* __restrict__ slist){
  int b = blockIdx.x;
  int tid = threadIdx.x;
  if (b < PRE_WB) {
    int g = b * 256 + tid;
    if (g < 1024) {
      int f = g >> 2, h = g & 3;
      const float4* wp = (const float4*)(W + f*HC + h*CDIM);
      const float4* ap = (const float4*)(att_src + h*CDIM);
      float s = 0.f;
      #pragma unroll 8
      for (int c4 = 0; c4 < CDIM/4; c4++){
        float4 wv = wp[c4], av = ap[c4];
        s += wv.x*av.x + wv.y*av.y + wv.z*av.z + wv.w*av.w;
      }
      ws_[g] = s;
    } else if (g < 2048) {
      int gg = g - 1024; int f = gg >> 2, h = gg & 3;
      const float4* wp = (const float4*)(W + f*HC + h*CDIM);
      const float4* ap = (const float4*)(att_dst + h*CDIM);
      float s = 0.f;
      #pragma unroll 8
      for (int c4 = 0; c4 < CDIM/4; c4++){
        float4 wv = wp[c4], av = ap[c4];
        s += wv.x*av.x + wv.y*av.y + wv.z*av.z + wv.w*av.w;
      }
      wd_[gg] = s;
    } else if (g < 2112) {
      int gg = g - 2048; int d = gg >> 2, h = gg & 3;
      const float4* wp = (const float4*)(W_edge + d*HC + h*CDIM);
      const float4* ap = (const float4*)(att_edge + h*CDIM);
      float s = 0.f;
      #pragma unroll 8
      for (int c4 = 0; c4 < CDIM/4; c4++){
        float4 wv = wp[c4], av = ap[c4];
        s += wv.x*av.x + wv.y*av.y + wv.z*av.z + wv.w*av.w;
      }
      we_[gg] = s;
    }
  } else if (b < PRE_EB) {
    // edge_attr partial column sums; col-group = idx & 3 (invariant under stride)
    int pb = b - PRE_WB;
    const float4* p = (const float4*)ea;
    const int total = NEDGES * 4;           // float4 count
    float4 acc = make_float4(0.f, 0.f, 0.f, 0.f);
    for (int i = pb*256 + tid; i < total; i += MPART*256){
      float4 v = p[i];
      acc.x += v.x; acc.y += v.y; acc.z += v.z; acc.w += v.w;
    }
    // reduce across the 16 lanes sharing lane&3
    #pragma unroll
    for (int off = 4; off <= 32; off <<= 1){
      acc.x += __shfl_xor(acc.x, off, 64);
      acc.y += __shfl_xor(acc.y, off, 64);
      acc.z += __shfl_xor(acc.z, off, 64);
      acc.w += __shfl_xor(acc.w, off, 64);
    }
    __shared__ float4 sd4[16];
    int lane = tid & 63, wave = tid >> 6;
    if (lane < 4) sd4[wave*4 + lane] = acc;
    __syncthreads();
    if (tid < 4){
      float4 t = sd4[tid];
      float4 a = sd4[4+tid], c = sd4[8+tid], d = sd4[12+tid];
      t.x += a.x + c.x + d.x; t.y += a.y + c.y + d.y;
      t.z += a.z + c.z + d.z; t.w += a.w + c.w + d.w;
      atomicAdd(&easum[4*tid+0], t.x);
      atomicAdd(&easum[4*tid+1], t.y);
      atomicAdd(&easum[4*tid+2], t.z);
      atomicAdd(&easum[4*tid+3], t.w);
    }
  } else {
    // binning: diagonal-dst edges -> slist[row*CAP+pos] = edge index
    int e = (b - PRE_EB)*256 + tid;
    int dst = ei[NEDGES + e];
    int r = dst % N2;
    if (r % 49) return;
    int row = (dst / N2) * NAG + r / 49;
    int pos = atomicAdd(&counts[row], 1);
    if (pos >= CAP) return;
    slist[row*CAP + pos] = e;
  }
}

// K2 (attn): 1 row/block, 512 threads (8 waves).
// Prologue: parallel resolve (tid<k): e -> src=ei[e], aed=ea[e]@we -> LDS.
// Then R10's 8-wave logit loop (srcs/aed now from LDS), softmax (waves 0-3),
// z-accum 8-way, combine, z -> global.
__global__ __launch_bounds__(512) void k_attn(const float* __restrict__ x,
    const int* __restrict__ ei, const float* __restrict__ ea,
    const float* __restrict__ ws_, const float* __restrict__ wd_,
    const float* __restrict__ we_, const float* __restrict__ easum,
    const int* __restrict__ counts, const int* __restrict__ slist,
    float* __restrict__ z){
  __shared__ float  lg[(CAP+1)*4];
  __shared__ int    srcs[CAP+1];
  __shared__ float  adst_s[4];
  __shared__ float  wesh[64];
  __shared__ float4 aedsh[CAP];
  __shared__ float4 pz[8*256];     // 32 KB per-wave z partials [wave][h*64+lane]
  int row = blockIdx.x;
  int tid = threadIdx.x;
  int lane = tid & 63, wave = tid >> 6;   // 8 waves
  int k = counts[row]; if (k > CAP) k = CAP;
  int g = row / NAG, j = row - g*NAG;
  int dst = g*N2 + j*49;

  if (tid < 64) wesh[tid] = we_[tid];
  __syncthreads();

  // parallel resolve: one thread per binned edge
  if (tid < k){
    int e = slist[row*CAP + tid];
    int src = ei[e];
    const float4* eap = (const float4*)(ea + (size_t)e*EDIM);
    float4 e0 = eap[0], e1 = eap[1], e2 = eap[2], e3 = eap[3];
    float a[4];
    #pragma unroll
    for (int h = 0; h < 4; h++){
      a[h] = e0.x*wesh[0*4+h]  + e0.y*wesh[1*4+h]  + e0.z*wesh[2*4+h]  + e0.w*wesh[3*4+h]
           + e1.x*wesh[4*4+h]  + e1.y*wesh[5*4+h]  + e1.z*wesh[6*4+h]  + e1.w*wesh[7*4+h]
           + e2.x*wesh[8*4+h]  + e2.y*wesh[9*4+h]  + e2.z*wesh[10*4+h] + e2.w*wesh[11*4+h]
           + e3.x*wesh[12*4+h] + e3.y*wesh[13*4+h] + e3.z*wesh[14*4+h] + e3.w*wesh[15*4+h];
    }
    srcs[tid] = src;
    aedsh[tid] = make_float4(a[0], a[1], a[2], a[3]);
  }
  __syncthreads();

  // per-lane slice of ws (f = lane*4+q, all 4 heads)
  float wsr[4][4];
  #pragma unroll
  for (int q = 0; q < 4; q++){
    float4 t = *(const float4*)(ws_ + (lane*4+q)*4);
    wsr[q][0]=t.x; wsr[q][1]=t.y; wsr[q][2]=t.z; wsr[q][3]=t.w;
  }

  // logits: 8 waves round-robin over edges (src + aed from LDS)
  for (int i = wave; i < k; i += 8){
    int src = srcs[i];
    float4 aedv = aedsh[i];
    float4 xv = *(const float4*)(x + (size_t)src*FIN + lane*4);
    float p0 = xv.x*wsr[0][0] + xv.y*wsr[1][0] + xv.z*wsr[2][0] + xv.w*wsr[3][0];
    float p1 = xv.x*wsr[0][1] + xv.y*wsr[1][1] + xv.z*wsr[2][1] + xv.w*wsr[3][1];
    float p2 = xv.x*wsr[0][2] + xv.y*wsr[1][2] + xv.z*wsr[2][2] + xv.w*wsr[3][2];
    float p3 = xv.x*wsr[0][3] + xv.y*wsr[1][3] + xv.z*wsr[2][3] + xv.w*wsr[3][3];
    p0 = wsum(p0); p1 = wsum(p1); p2 = wsum(p2); p3 = wsum(p3);
    if (lane == 0){
      lg[i*4+0] = p0 + aedv.x; lg[i*4+1] = p1 + aedv.y;
      lg[i*4+2] = p2 + aedv.z; lg[i*4+3] = p3 + aedv.w;
    }
  }

  // wave 0: a_dst, self-loop logit (a_src(dst) + mean_ea@we)
  if (wave == 0){
    float wdr[4][4];
    #pragma unroll
    for (int q = 0; q < 4; q++){
      float4 t = *(const float4*)(wd_ + (lane*4+q)*4);
      wdr[q][0]=t.x; wdr[q][1]=t.y; wdr[q][2]=t.z; wdr[q][3]=t.w;
    }
    float4 xv = *(const float4*)(x + (size_t)dst*FIN + lane*4);
    float pd[4], ps[4];
    #pragma unroll
    for (int h = 0; h < 4; h++){
      pd[h] = xv.x*wdr[0][h] + xv.y*wdr[1][h] + xv.z*wdr[2][h] + xv.w*wdr[3][h];
      ps[h] = xv.x*wsr[0][h] + xv.y*wsr[1][h] + xv.z*wsr[2][h] + xv.w*wsr[3][h];
    }
    const float invE = 1.0f/(float)NEDGES;
    float md = (lane < 16) ? easum[lane]*invE : 0.f;
    float al[4];
    #pragma unroll
    for (int h = 0; h < 4; h++){
      float c = (lane < 16) ? md*wesh[lane*4+h] : 0.f;
      al[h] = wsum(c);
      pd[h] = wsum(pd[h]);
      ps[h] = wsum(ps[h]);
    }
    if (lane == 0){
      #pragma unroll
      for (int h = 0; h < 4; h++){
        adst_s[h] = pd[h];
        lg[k*4+h] = ps[h] + al[h];
      }
      srcs[k] = dst;   // self-loop src for unified z-accumulation
    }
  }
  __syncthreads();

  // segment softmax: waves 0-3, wave = head
  if (wave < 4){
    int h = wave;
    float ad = adst_s[h];
    float m = -1e30f;
    for (int i = lane; i <= k; i += 64){
      float v = lrelu(lg[i*4+h] + ad, 0.2f);
      lg[i*4+h] = v;
      m = fmaxf(m, v);
    }
    m = wmax(m);
    float s = 0.f;
    for (int i = lane; i <= k; i += 64){
      float e = __expf(lg[i*4+h] - m);
      lg[i*4+h] = e;
      s += e;
    }
    s = wsum(s);
    float inv = 1.0f/(s + 1e-16f);
    for (int i = lane; i <= k; i += 64) lg[i*4+h] *= inv;
  }
  __syncthreads();

  // z accumulation: wave w handles edges i = w, w+8, ... (incl self at i=k)
  {
    float acc[4][4];
    #pragma unroll
    for (int h = 0; h < 4; h++)
      #pragma unroll
      for (int c = 0; c < 4; c++) acc[h][c] = 0.f;
    for (int i = wave; i <= k; i += 8){
      int src = srcs[i];
      float4 xv = *(const float4*)(x + (size_t)src*FIN + lane*4);
      float a0 = lg[i*4+0], a1 = lg[i*4+1], a2 = lg[i*4+2], a3 = lg[i*4+3];
      acc[0][0] += a0*xv.x; acc[0][1] += a0*xv.y; acc[0][2] += a0*xv.z; acc[0][3] += a0*xv.w;
      acc[1][0] += a1*xv.x; acc[1][1] += a1*xv.y; acc[1][2] += a1*xv.z; acc[1][3] += a1*xv.w;
      acc[2][0] += a2*xv.x; acc[2][1] += a2*xv.y; acc[2][2] += a2*xv.z; acc[2][3] += a2*xv.w;
      acc[3][0] += a3*xv.x; acc[3][1] += a3*xv.y; acc[3][2] += a3*xv.z; acc[3][3] += a3*xv.w;
    }
    #pragma unroll
    for (int h = 0; h < 4; h++)
      pz[wave*256 + h*64 + lane] =
        make_float4(acc[h][0], acc[h][1], acc[h][2], acc[h][3]);
  }
  __syncthreads();
  if (tid < 256){
    float4 s0 = pz[tid];
    #pragma unroll
    for (int w = 1; w < 8; w++){
      float4 t = pz[w*256 + tid];
      s0.x += t.x; s0.y += t.y; s0.z += t.z; s0.w += t.w;
    }
    ((float4*)(z + (size_t)row*1024))[tid] = s0;
  }
}

// K3 (gemm1): block (rb, h) = rows 8rb..8rb+7 x head h's 128 cols.
// Each W float4 read once per block (slice 128 KB). z transposed in LDS.
__global__ __launch_bounds__(256) void k_gemm1(const float* __restrict__ z,
    const float* __restrict__ W, const float* __restrict__ bias,
    float* __restrict__ h2){
  __shared__ float  zt[256][8];        //  8 KB transposed z: zt[f][r]
  __shared__ float4 part[8][8][32];    // 32 KB partials [q][r][cg]
  int rb = blockIdx.x * 8;
  int h  = blockIdx.y;
  int tid = threadIdx.x;
  for (int idx = tid; idx < 2048; idx += 256){
    int r = idx >> 8, f = idx & 255;
    zt[f][r] = z[(size_t)(rb+r)*1024 + h*256 + f];
  }
  __syncthreads();
  {
    int cg = tid & 31, q = tid >> 5;
    const float4* Wp = (const float4*)(W + h*CDIM) + cg;
    float4 acc[8];
    #pragma unroll
    for (int r = 0; r < 8; r++) acc[r] = make_float4(0.f,0.f,0.f,0.f);
    int f0 = q*32;
    #pragma unroll 8
    for (int jf = 0; jf < 32; jf++){
      int f = f0 + jf;
      float4 w4 = Wp[(size_t)f*(HC/4)];
      float4 zlo = *(const float4*)&zt[f][0];
      float4 zhi = *(const float4*)&zt[f][4];
      acc[0].x += zlo.x*w4.x; acc[0].y += zlo.x*w4.y; acc[0].z += zlo.x*w4.z; acc[0].w += zlo.x*w4.w;
      acc[1].x += zlo.y*w4.x; acc[1].y += zlo.y*w4.y; acc[1].z += zlo.y*w4.z; acc[1].w += zlo.y*w4.w;
      acc[2].x += zlo.z*w4.x; acc[2].y += zlo.z*w4.y; acc[2].z += zlo.z*w4.z; acc[2].w += zlo.z*w4.w;
      acc[3].x += zlo.w*w4.x; acc[3].y += zlo.w*w4.y; acc[3].z += zlo.w*w4.z; acc[3].w += zlo.w*w4.w;
      acc[4].x += zhi.x*w4.x; acc[4].y += zhi.x*w4.y; acc[4].z += zhi.x*w4.z; acc[4].w += zhi.x*w4.w;
      acc[5].x += zhi.y*w4.x; acc[5].y += zhi.y*w4.y; acc[5].z += zhi.y*w4.z; acc[5].w += zhi.y*w4.w;
      acc[6].x += zhi.z*w4.x; acc[6].y += zhi.z*w4.y; acc[6].z += zhi.z*w4.z; acc[6].w += zhi.z*w4.w;
      acc[7].x += zhi.w*w4.x; acc[7].y += zhi.w*w4.y; acc[7].z += zhi.w*w4.z; acc[7].w += zhi.w*w4.w;
    }
    #pragma unroll
    for (int r = 0; r < 8; r++) part[q][r][cg] = acc[r];
  }
  __syncthreads();
  {
    int r = tid >> 5, cg = tid & 31;   // 8 rows x 32 col-groups = 256 outputs
    float4 s0 = part[0][r][cg];
    #pragma unroll
    for (int q = 1; q < 8; q++){
      float4 t = part[q][r][cg];
      s0.x += t.x; s0.y += t.y; s0.z += t.z; s0.w += t.w;
    }
    float4 bs = ((const float4*)bias)[h*32 + cg];
    float4 o;
    o.x = lrelu(s0.x+bs.x, 0.01f);
    o.y = lrelu(s0.y+bs.y, 0.01f);
    o.z = lrelu(s0.z+bs.z, 0.01f);
    o.w = lrelu(s0.w+bs.w, 0.01f);
    *(float4*)(h2 + (size_t)(rb+r)*HC + h*CDIM + 4*cg) = o;
  }
}

// K4 (gemm2): block (rb, cb) = rows 8rb..8rb+7 x cols 64cb..64cb+63.
// fcW slice 128 KB/block, each float4 read once. h2 transposed in LDS.
__global__ __launch_bounds__(256) void k_gemm2(const float* __restrict__ h2,
    const float* __restrict__ fcW, const float* __restrict__ fcb,
    float* __restrict__ out){
  __shared__ float  ht[512][8];        // 16 KB transposed h2: ht[kf][r]
  __shared__ float4 part[16][8][16];   // 32 KB partials [q][r][cg]
  int rb = blockIdx.x * 8;
  int cb = blockIdx.y;
  int tid = threadIdx.x;
  for (int idx = tid; idx < 4096; idx += 256){
    int r = idx >> 9, kf = idx & 511;
    ht[kf][r] = h2[(size_t)(rb+r)*HC + kf];
  }
  __syncthreads();
  {
    int cg = tid & 15, q = tid >> 4;
    const float4* Fp = (const float4*)(fcW + cb*64) + cg;
    float4 acc[8];
    #pragma unroll
    for (int r = 0; r < 8; r++) acc[r] = make_float4(0.f,0.f,0.f,0.f);
    int k0 = q*32;
    #pragma unroll 8
    for (int jk = 0; jk < 32; jk++){
      int kf = k0 + jk;
      float4 w4 = Fp[(size_t)kf*64];
      float4 hlo = *(const float4*)&ht[kf][0];
      float4 hhi = *(const float4*)&ht[kf][4];
      acc[0].x += hlo.x*w4.x; acc[0].y += hlo.x*w4.y; acc[0].z += hlo.x*w4.z; acc[0].w += hlo.x*w4.w;
      acc[1].x += hlo.y*w4.x; acc[1].y += hlo.y*w4.y; acc[1].z += hlo.y*w4.z; acc[1].w += hlo.y*w4.w;
      acc[2].x += hlo.z*w4.x; acc[2].y += hlo.z*w4.y; acc[2].z += hlo.z*w4.z; acc[2].w += hlo.z*w4.w;
      acc[3].x += hlo.w*w4.x; acc[3].y += hlo.w*w4.y; acc[3].z += hlo.w*w4.z; acc[3].w += hlo.w*w4.w;
      acc[4].x += hhi.x*w4.x; acc[4].y += hhi.x*w4.y; acc[4].z += hhi.x*w4.z; acc[4].w += hhi.x*w4.w;
      acc[5].x += hhi.y*w4.x; acc[5].y += hhi.y*w4.y; acc[5].z += hhi.y*w4.z; acc[5].w += hhi.y*w4.w;
      acc[6].x += hhi.z*w4.x; acc[6].y += hhi.z*w4.y; acc[6].z += hhi.z*w4.z; acc[6].w += hhi.z*w4.w;
      acc[7].x += hhi.w*w4.x; acc[7].y += hhi.w*w4.y; acc[7].z += hhi.w*w4.z; acc[7].w += hhi.w*w4.w;
    }
    #pragma unroll
    for (int r = 0; r < 8; r++) part[q][r][cg] = acc[r];
  }
  __syncthreads();
  if (tid < 128){
    int r = tid >> 4, cg = tid & 15;   // 8 rows x 16 col-groups = 128 outputs
    float4 s0 = part[0][r][cg];
    #pragma unroll
    for (int q = 1; q < 16; q++){
      float4 t = part[q][r][cg];
      s0.x += t.x; s0.y += t.y; s0.z += t.z; s0.w += t.w;
    }
    float4 bs = ((const float4*)fcb)[cb*16 + cg];
    float4 o;
    o.x = lrelu(s0.x+bs.x, 0.01f);
    o.y = lrelu(s0.y+bs.y, 0.01f);
    o.z = lrelu(s0.z+bs.z, 0.01f);
    o.w = lrelu(s0.w+bs.w, 0.01f);
    *(float4*)(out + (size_t)(rb+r)*256 + cb*64 + 4*cg) = o;
  }
}

extern "C" void kernel_launch(void* const* d_in, const int* in_sizes, int n_in,
                              void* d_out, int out_size, void* d_ws, size_t ws_size,
                              hipStream_t stream) {
  const float* x        = (const float*)d_in[0];
  const int*   ei       = (const int*)  d_in[1];
  const float* ea       = (const float*)d_in[2];
  // d_in[3]=num_groups, d_in[4]=agents_per_group (fixed: 12, 48)
  const float* W        = (const float*)d_in[5];
  const float* att_src  = (const float*)d_in[6];
  const float* att_dst  = (const float*)d_in[7];
  const float* W_edge   = (const float*)d_in[8];
  const float* att_edge = (const float*)d_in[9];
  const float* bias     = (const float*)d_in[10];
  const float* fcW      = (const float*)d_in[11];
  const float* fcb      = (const float*)d_in[12];
  float* out = (float*)d_out;

  float* w = (float*)d_ws;
  float*  ws_       = w;                    // 1024
  float*  wd_       = w + 1024;             // 1024
  float*  we_       = w + 2048;             // 64
  float*  easum     = w + 2112;             // 16  (zeroed by memset)
  int*    counts    = (int*)(w + 2128);     // 576 (zeroed by memset, adjacent)
  int*    slist     = (int*)(w + 2704);     // 576*128 = 73728 (edge indices)
  float*  z         = w + 76432;            // 576*1024 = 589824 (16B-aligned)
  float*  h2        = w + 666256;           // 576*512 = 294912  (16B-aligned)

  hipMemsetAsync(easum, 0, (16 + NOUT)*sizeof(float), stream);
  k_pre<<<PREB, 256, 0, stream>>>(W, att_src, att_dst, W_edge, att_edge, ea, ei,
                                  ws_, wd_, we_, easum, counts, slist);
  k_attn<<<NOUT, 512, 0, stream>>>(x, ei, ea, ws_, wd_, we_, easum,
                                   counts, slist, z);
  k_gemm1<<<dim3(NOUT/8, 4), 256, 0, stream>>>(z, W, bias, h2);
  k_gemm2<<<dim3(NOUT/8, 4), 256, 0, stream>>>(h2, fcW, fcb, out);
}

// Round 12
// 146.951 us; speedup vs baseline: 1.1066x; 1.1066x over previous
//
#include <hip/hip_runtime.h>

// Problem constants (fixed by setup_inputs)
#define NNODES 27648
#define NEDGES 442368
#define FIN    256
#define HC     512
#define NH     4
#define CDIM   128
#define NAG    48
#define NGRP   12
#define N2     2304    // 48*48
#define NOUT   576     // 12*48
#define CAP    128     // max edges kept per output row (Poisson mean ~16)
#define EDIM   16
#define MPART  512     // meansum partial blocks

// R12 = R10 byte-identical revert (best measured: 147.3 us).
// R9 (+17.9) and R11 (+15.3) both showed the memset+merged-binning family
// regresses ~15 us despite favorable work arithmetic — kernel-count is not
// the cost driver in this harness. R10's composition: R5 pre/scan (src
// resolved + aed precomputed in the throughput pass), 8-wave k_attn,
// R8 column-split gemm tail.

__device__ __forceinline__ float lrelu(float v, float s){ return v > 0.0f ? v : s * v; }

__device__ __forceinline__ float wsum(float v){
  #pragma unroll
  for (int off = 32; off; off >>= 1) v += __shfl_xor(v, off, 64);
  return v;
}
__device__ __forceinline__ float wmax(float v){
  #pragma unroll
  for (int off = 32; off; off >>= 1) v = fmaxf(v, __shfl_xor(v, off, 64));
  return v;
}

// K_A (fused): blocks 0..10  -> ws/wd/we precompute + zero counts
//              blocks 11..   -> edge_attr column partial sums (float4, grid-stride)
__global__ __launch_bounds__(256) void k_pre(
    const float* __restrict__ W, const float* __restrict__ att_src,
    const float* __restrict__ att_dst, const float* __restrict__ W_edge,
    const float* __restrict__ att_edge, const float* __restrict__ ea,
    float* __restrict__ ws_, float* __restrict__ wd_, float* __restrict__ we_,
    int* __restrict__ counts, float4* __restrict__ easum_part){
  int b = blockIdx.x;
  int tid = threadIdx.x;
  if (b < 11) {
    int g = b * 256 + tid;
    if (g < 1024) {
      int f = g >> 2, h = g & 3;
      const float4* wp = (const float4*)(W + f*HC + h*CDIM);
      const float4* ap = (const float4*)(att_src + h*CDIM);
      float s = 0.f;
      #pragma unroll 8
      for (int c4 = 0; c4 < CDIM/4; c4++){
        float4 wv = wp[c4], av = ap[c4];
        s += wv.x*av.x + wv.y*av.y + wv.z*av.z + wv.w*av.w;
      }
      ws_[g] = s;
    } else if (g < 2048) {
      int gg = g - 1024; int f = gg >> 2, h = gg & 3;
      const float4* wp = (const float4*)(W + f*HC + h*CDIM);
      const float4* ap = (const float4*)(att_dst + h*CDIM);
      float s = 0.f;
      #pragma unroll 8
      for (int c4 = 0; c4 < CDIM/4; c4++){
        float4 wv = wp[c4], av = ap[c4];
        s += wv.x*av.x + wv.y*av.y + wv.z*av.z + wv.w*av.w;
      }
      wd_[gg] = s;
    } else if (g < 2112) {
      int gg = g - 2048; int d = gg >> 2, h = gg & 3;
      const float4* wp = (const float4*)(W_edge + d*HC + h*CDIM);
      const float4* ap = (const float4*)(att_edge + h*CDIM);
      float s = 0.f;
      #pragma unroll 8
      for (int c4 = 0; c4 < CDIM/4; c4++){
        float4 wv = wp[c4], av = ap[c4];
        s += wv.x*av.x + wv.y*av.y + wv.z*av.z + wv.w*av.w;
      }
      we_[gg] = s;
    } else if (g < 2112 + NOUT) {
      counts[g - 2112] = 0;
    }
  } else {
    // edge_attr partial column sums; col-group = idx & 3 (invariant under stride)
    int pb = b - 11;
    const float4* p = (const float4*)ea;
    const int total = NEDGES * 4;           // float4 count
    float4 acc = make_float4(0.f, 0.f, 0.f, 0.f);
    for (int i = pb*256 + tid; i < total; i += MPART*256){
      float4 v = p[i];
      acc.x += v.x; acc.y += v.y; acc.z += v.z; acc.w += v.w;
    }
    // reduce across the 16 lanes sharing lane&3
    #pragma unroll
    for (int off = 4; off <= 32; off <<= 1){
      acc.x += __shfl_xor(acc.x, off, 64);
      acc.y += __shfl_xor(acc.y, off, 64);
      acc.z += __shfl_xor(acc.z, off, 64);
      acc.w += __shfl_xor(acc.w, off, 64);
    }
    __shared__ float4 sd4[16];
    int lane = tid & 63, wave = tid >> 6;
    if (lane < 4) sd4[wave*4 + lane] = acc;
    __syncthreads();
    if (tid < 4){
      float4 t = sd4[tid];
      float4 a = sd4[4+tid], c = sd4[8+tid], d = sd4[12+tid];
      t.x += a.x + c.x + d.x; t.y += a.y + c.y + d.y;
      t.z += a.z + c.z + d.z; t.w += a.w + c.w + d.w;
      easum_part[pb*4 + tid] = t;
    }
  }
}

// K_B: blocks 0..1727 bin edges whose dst is diagonal (slist = resolved src,
// aed = ea@we precomputed); block 1728 reduces easum.
__global__ __launch_bounds__(256) void k_scan(const int* __restrict__ ei,
    const float* __restrict__ ea, const float* __restrict__ we_,
    int* __restrict__ counts, int* __restrict__ slist, float* __restrict__ aed,
    const float* __restrict__ easum_part, float* __restrict__ easum){
  int tid = threadIdx.x;
  if (blockIdx.x == NEDGES/256){
    // reduce 512 partial blocks x 16 cols -> easum[16]
    int col = tid & 15, part = tid >> 4;          // 16 parts x 32 pblocks
    float s = 0.f;
    for (int pb = 0; pb < MPART/16; pb++)
      s += easum_part[(part*(MPART/16) + pb)*16 + col];
    __shared__ float sd[256];
    sd[tid] = s;
    __syncthreads();
    if (tid < 16){
      float t = 0.f;
      #pragma unroll
      for (int i = 0; i < 16; i++) t += sd[i*16 + tid];
      easum[tid] = t;
    }
    return;
  }
  int e = blockIdx.x*256 + tid;
  int dst = ei[NEDGES + e];
  int r = dst % N2;
  if (r % 49) return;
  int row = (dst / N2) * NAG + r / 49;
  int pos = atomicAdd(&counts[row], 1);
  if (pos >= CAP) return;
  slist[row*CAP + pos] = ei[e];
  const float* eap = ea + (size_t)e*EDIM;
  float a0=0.f,a1=0.f,a2=0.f,a3=0.f;
  #pragma unroll
  for (int d = 0; d < EDIM; d++){
    float v = eap[d];
    a0 += v*we_[d*4+0]; a1 += v*we_[d*4+1]; a2 += v*we_[d*4+2]; a3 += v*we_[d*4+3];
  }
  float* ap = aed + (size_t)(row*CAP+pos)*4;
  ap[0]=a0; ap[1]=a1; ap[2]=a2; ap[3]=a3;
}

// K_C (attn): 1 row/block, 512 threads (8 waves). On-the-fly logits from
// resolved slist + precomputed aed (R5's fast structure), round-robin depth
// ~k/8. Softmax on waves 0-3 (wave = head). z-accum 8-way, combine, z->global.
__global__ __launch_bounds__(512) void k_attn(const float* __restrict__ x,
    const float* __restrict__ ws_, const float* __restrict__ wd_,
    const float* __restrict__ we_, const float* __restrict__ easum,
    const int* __restrict__ counts, const int* __restrict__ slist,
    const float* __restrict__ aed, float* __restrict__ z){
  __shared__ float  lg[(CAP+1)*4];
  __shared__ int    srcs[CAP+1];
  __shared__ float  adst_s[4];
  __shared__ float4 pz[8*256];     // 32 KB per-wave z partials [wave][h*64+lane]
  int row = blockIdx.x;
  int tid = threadIdx.x;
  int lane = tid & 63, wave = tid >> 6;   // 8 waves
  int k = counts[row]; if (k > CAP) k = CAP;
  int g = row / NAG, j = row - g*NAG;
  int dst = g*N2 + j*49;

  // per-lane slice of ws (f = lane*4+q, all 4 heads)
  float wsr[4][4];
  #pragma unroll
  for (int q = 0; q < 4; q++){
    float4 t = *(const float4*)(ws_ + (lane*4+q)*4);
    wsr[q][0]=t.x; wsr[q][1]=t.y; wsr[q][2]=t.z; wsr[q][3]=t.w;
  }

  // logits: 8 waves round-robin over edges (src pre-resolved, aed 16B)
  for (int i = wave; i < k; i += 8){
    int src = slist[row*CAP + i];
    float4 aedv = *(const float4*)(aed + (size_t)(row*CAP+i)*4);
    float4 xv = *(const float4*)(x + (size_t)src*FIN + lane*4);
    float p0 = xv.x*wsr[0][0] + xv.y*wsr[1][0] + xv.z*wsr[2][0] + xv.w*wsr[3][0];
    float p1 = xv.x*wsr[0][1] + xv.y*wsr[1][1] + xv.z*wsr[2][1] + xv.w*wsr[3][1];
    float p2 = xv.x*wsr[0][2] + xv.y*wsr[1][2] + xv.z*wsr[2][2] + xv.w*wsr[3][2];
    float p3 = xv.x*wsr[0][3] + xv.y*wsr[1][3] + xv.z*wsr[2][3] + xv.w*wsr[3][3];
    p0 = wsum(p0); p1 = wsum(p1); p2 = wsum(p2); p3 = wsum(p3);
    if (lane == 0){
      srcs[i] = src;
      lg[i*4+0] = p0 + aedv.x; lg[i*4+1] = p1 + aedv.y;
      lg[i*4+2] = p2 + aedv.z; lg[i*4+3] = p3 + aedv.w;
    }
  }

  // wave 0: a_dst, self-loop logit (a_src(dst) + mean_ea@we)
  if (wave == 0){
    float wdr[4][4];
    #pragma unroll
    for (int q = 0; q < 4; q++){
      float4 t = *(const float4*)(wd_ + (lane*4+q)*4);
      wdr[q][0]=t.x; wdr[q][1]=t.y; wdr[q][2]=t.z; wdr[q][3]=t.w;
    }
    float4 xv = *(const float4*)(x + (size_t)dst*FIN + lane*4);
    float pd[4], ps[4];
    #pragma unroll
    for (int h = 0; h < 4; h++){
      pd[h] = xv.x*wdr[0][h] + xv.y*wdr[1][h] + xv.z*wdr[2][h] + xv.w*wdr[3][h];
      ps[h] = xv.x*wsr[0][h] + xv.y*wsr[1][h] + xv.z*wsr[2][h] + xv.w*wsr[3][h];
    }
    const float invE = 1.0f/(float)NEDGES;
    float md = (lane < 16) ? easum[lane]*invE : 0.f;
    float al[4];
    #pragma unroll
    for (int h = 0; h < 4; h++){
      float c = (lane < 16) ? md*we_[lane*4+h] : 0.f;
      al[h] = wsum(c);
      pd[h] = wsum(pd[h]);
      ps[h] = wsum(ps[h]);
    }
    if (lane == 0){
      #pragma unroll
      for (int h = 0; h < 4; h++){
        adst_s[h] = pd[h];
        lg[k*4+h] = ps[h] + al[h];
      }
      srcs[k] = dst;   // self-loop src for unified z-accumulation
    }
  }
  __syncthreads();

  // segment softmax: waves 0-3, wave = head
  if (wave < 4){
    int h = wave;
    float ad = adst_s[h];
    float m = -1e30f;
    for (int i = lane; i <= k; i += 64){
      float v = lrelu(lg[i*4+h] + ad, 0.2f);
      lg[i*4+h] = v;
      m = fmaxf(m, v);
    }
    m = wmax(m);
    float s = 0.f;
    for (int i = lane; i <= k; i += 64){
      float e = __expf(lg[i*4+h] - m);
      lg[i*4+h] = e;
      s += e;
    }
    s = wsum(s);
    float inv = 1.0f/(s + 1e-16f);
    for (int i = lane; i <= k; i += 64) lg[i*4+h] *= inv;
  }
  __syncthreads();

  // z accumulation: wave w handles edges i = w, w+8, ... (incl self at i=k)
  {
    float acc[4][4];
    #pragma unroll
    for (int h = 0; h < 4; h++)
      #pragma unroll
      for (int c = 0; c < 4; c++) acc[h][c] = 0.f;
    for (int i = wave; i <= k; i += 8){
      int src = srcs[i];
      float4 xv = *(const float4*)(x + (size_t)src*FIN + lane*4);
      float a0 = lg[i*4+0], a1 = lg[i*4+1], a2 = lg[i*4+2], a3 = lg[i*4+3];
      acc[0][0] += a0*xv.x; acc[0][1] += a0*xv.y; acc[0][2] += a0*xv.z; acc[0][3] += a0*xv.w;
      acc[1][0] += a1*xv.x; acc[1][1] += a1*xv.y; acc[1][2] += a1*xv.z; acc[1][3] += a1*xv.w;
      acc[2][0] += a2*xv.x; acc[2][1] += a2*xv.y; acc[2][2] += a2*xv.z; acc[2][3] += a2*xv.w;
      acc[3][0] += a3*xv.x; acc[3][1] += a3*xv.y; acc[3][2] += a3*xv.z; acc[3][3] += a3*xv.w;
    }
    #pragma unroll
    for (int h = 0; h < 4; h++)
      pz[wave*256 + h*64 + lane] =
        make_float4(acc[h][0], acc[h][1], acc[h][2], acc[h][3]);
  }
  __syncthreads();
  if (tid < 256){
    float4 s0 = pz[tid];
    #pragma unroll
    for (int w = 1; w < 8; w++){
      float4 t = pz[w*256 + tid];
      s0.x += t.x; s0.y += t.y; s0.z += t.z; s0.w += t.w;
    }
    ((float4*)(z + (size_t)row*1024))[tid] = s0;
  }
}

// K_D (gemm1): block (rb, h) = rows 8rb..8rb+7 x head h's 128 cols.
// Each W float4 read once per block (slice 128 KB). z transposed in LDS.
__global__ __launch_bounds__(256) void k_gemm1(const float* __restrict__ z,
    const float* __restrict__ W, const float* __restrict__ bias,
    float* __restrict__ h2){
  __shared__ float  zt[256][8];        //  8 KB transposed z: zt[f][r]
  __shared__ float4 part[8][8][32];    // 32 KB partials [q][r][cg]
  int rb = blockIdx.x * 8;
  int h  = blockIdx.y;
  int tid = threadIdx.x;
  for (int idx = tid; idx < 2048; idx += 256){
    int r = idx >> 8, f = idx & 255;
    zt[f][r] = z[(size_t)(rb+r)*1024 + h*256 + f];
  }
  __syncthreads();
  {
    int cg = tid & 31, q = tid >> 5;
    const float4* Wp = (const float4*)(W + h*CDIM) + cg;
    float4 acc[8];
    #pragma unroll
    for (int r = 0; r < 8; r++) acc[r] = make_float4(0.f,0.f,0.f,0.f);
    int f0 = q*32;
    #pragma unroll 8
    for (int jf = 0; jf < 32; jf++){
      int f = f0 + jf;
      float4 w4 = Wp[(size_t)f*(HC/4)];
      float4 zlo = *(const float4*)&zt[f][0];
      float4 zhi = *(const float4*)&zt[f][4];
      acc[0].x += zlo.x*w4.x; acc[0].y += zlo.x*w4.y; acc[0].z += zlo.x*w4.z; acc[0].w += zlo.x*w4.w;
      acc[1].x += zlo.y*w4.x; acc[1].y += zlo.y*w4.y; acc[1].z += zlo.y*w4.z; acc[1].w += zlo.y*w4.w;
      acc[2].x += zlo.z*w4.x; acc[2].y += zlo.z*w4.y; acc[2].z += zlo.z*w4.z; acc[2].w += zlo.z*w4.w;
      acc[3].x += zlo.w*w4.x; acc[3].y += zlo.w*w4.y; acc[3].z += zlo.w*w4.z; acc[3].w += zlo.w*w4.w;
      acc[4].x += zhi.x*w4.x; acc[4].y += zhi.x*w4.y; acc[4].z += zhi.x*w4.z; acc[4].w += zhi.x*w4.w;
      acc[5].x += zhi.y*w4.x; acc[5].y += zhi.y*w4.y; acc[5].z += zhi.y*w4.z; acc[5].w += zhi.y*w4.w;
      acc[6].x += zhi.z*w4.x; acc[6].y += zhi.z*w4.y; acc[6].z += zhi.z*w4.z; acc[6].w += zhi.z*w4.w;
      acc[7].x += zhi.w*w4.x; acc[7].y += zhi.w*w4.y; acc[7].z += zhi.w*w4.z; acc[7].w += zhi.w*w4.w;
    }
    #pragma unroll
    for (int r = 0; r < 8; r++) part[q][r][cg] = acc[r];
  }
  __syncthreads();
  {
    int r = tid >> 5, cg = tid & 31;   // 8 rows x 32 col-groups = 256 outputs
    float4 s0 = part[0][r][cg];
    #pragma unroll
    for (int q = 1; q < 8; q++){
      float4 t = part[q][r][cg];
      s0.x += t.x; s0.y += t.y; s0.z += t.z; s0.w += t.w;
    }
    float4 bs = ((const float4*)bias)[h*32 + cg];
    float4 o;
    o.x = lrelu(s0.x+bs.x, 0.01f);
    o.y = lrelu(s0.y+bs.y, 0.01f);
    o.z = lrelu(s0.z+bs.z, 0.01f);
    o.w = lrelu(s0.w+bs.w, 0.01f);
    *(float4*)(h2 + (size_t)(rb+r)*HC + h*CDIM + 4*cg) = o;
  }
}

// K_E (gemm2): block (rb, cb) = rows 8rb..8rb+7 x cols 64cb..64cb+63.
// fcW slice 128 KB/block, each float4 read once. h2 transposed in LDS.
__global__ __launch_bounds__(256) void k_gemm2(const float* __restrict__ h2,
    const float* __restrict__ fcW, const float* __restrict__ fcb,
    float* __restrict__ out){
  __shared__ float  ht[512][8];        // 16 KB transposed h2: ht[kf][r]
  __shared__ float4 part[16][8][16];   // 32 KB partials [q][r][cg]
  int rb = blockIdx.x * 8;
  int cb = blockIdx.y;
  int tid = threadIdx.x;
  for (int idx = tid; idx < 4096; idx += 256){
    int r = idx >> 9, kf = idx & 511;
    ht[kf][r] = h2[(size_t)(rb+r)*HC + kf];
  }
  __syncthreads();
  {
    int cg = tid & 15, q = tid >> 4;
    const float4* Fp = (const float4*)(fcW + cb*64) + cg;
    float4 acc[8];
    #pragma unroll
    for (int r = 0; r < 8; r++) acc[r] = make_float4(0.f,0.f,0.f,0.f);
    int k0 = q*32;
    #pragma unroll 8
    for (int jk = 0; jk < 32; jk++){
      int kf = k0 + jk;
      float4 w4 = Fp[(size_t)kf*64];
      float4 hlo = *(const float4*)&ht[kf][0];
      float4 hhi = *(const float4*)&ht[kf][4];
      acc[0].x += hlo.x*w4.x; acc[0].y += hlo.x*w4.y; acc[0].z += hlo.x*w4.z; acc[0].w += hlo.x*w4.w;
      acc[1].x += hlo.y*w4.x; acc[1].y += hlo.y*w4.y; acc[1].z += hlo.y*w4.z; acc[1].w += hlo.y*w4.w;
      acc[2].x += hlo.z*w4.x; acc[2].y += hlo.z*w4.y; acc[2].z += hlo.z*w4.z; acc[2].w += hlo.z*w4.w;
      acc[3].x += hlo.w*w4.x; acc[3].y += hlo.w*w4.y; acc[3].z += hlo.w*w4.z; acc[3].w += hlo.w*w4.w;
      acc[4].x += hhi.x*w4.x; acc[4].y += hhi.x*w4.y; acc[4].z += hhi.x*w4.z; acc[4].w += hhi.x*w4.w;
      acc[5].x += hhi.y*w4.x; acc[5].y += hhi.y*w4.y; acc[5].z += hhi.y*w4.z; acc[5].w += hhi.y*w4.w;
      acc[6].x += hhi.z*w4.x; acc[6].y += hhi.z*w4.y; acc[6].z += hhi.z*w4.z; acc[6].w += hhi.z*w4.w;
      acc[7].x += hhi.w*w4.x; acc[7].y += hhi.w*w4.y; acc[7].z += hhi.w*w4.z; acc[7].w += hhi.w*w4.w;
    }
    #pragma unroll
    for (int r = 0; r < 8; r++) part[q][r][cg] = acc[r];
  }
  __syncthreads();
  if (tid < 128){
    int r = tid >> 4, cg = tid & 15;   // 8 rows x 16 col-groups = 128 outputs
    float4 s0 = part[0][r][cg];
    #pragma unroll
    for (int q = 1; q < 16; q++){
      float4 t = part[q][r][cg];
      s0.x += t.x; s0.y += t.y; s0.z += t.z; s0.w += t.w;
    }
    float4 bs = ((const float4*)fcb)[cb*16 + cg];
    float4 o;
    o.x = lrelu(s0.x+bs.x, 0.01f);
    o.y = lrelu(s0.y+bs.y, 0.01f);
    o.z = lrelu(s0.z+bs.z, 0.01f);
    o.w = lrelu(s0.w+bs.w, 0.01f);
    *(float4*)(out + (size_t)(rb+r)*256 + cb*64 + 4*cg) = o;
  }
}

extern "C" void kernel_launch(void* const* d_in, const int* in_sizes, int n_in,
                              void* d_out, int out_size, void* d_ws, size_t ws_size,
                              hipStream_t stream) {
  const float* x        = (const float*)d_in[0];
  const int*   ei       = (const int*)  d_in[1];
  const float* ea       = (const float*)d_in[2];
  // d_in[3]=num_groups, d_in[4]=agents_per_group (fixed: 12, 48)
  const float* W        = (const float*)d_in[5];
  const float* att_src  = (const float*)d_in[6];
  const float* att_dst  = (const float*)d_in[7];
  const float* W_edge   = (const float*)d_in[8];
  const float* att_edge = (const float*)d_in[9];
  const float* bias     = (const float*)d_in[10];
  const float* fcW      = (const float*)d_in[11];
  const float* fcb      = (const float*)d_in[12];
  float* out = (float*)d_out;

  float* w = (float*)d_ws;
  float*  ws_       = w;                    // 1024
  float*  wd_       = w + 1024;             // 1024
  float*  we_       = w + 2048;             // 64
  float*  easum     = w + 2112;             // 16
  int*    counts    = (int*)(w + 2128);     // 576
  float*  easum_p   = w + 2704;             // 512*16 = 8192 (16B-aligned)
  int*    slist     = (int*)(w + 10896);    // 576*128 = 73728 (resolved src)
  float*  aed       = w + 84624;            // 576*128*4 = 294912 (16B-aligned)
  float*  z         = w + 379536;           // 576*1024 = 589824 (16B-aligned)
  float*  h2        = w + 969360;           // 576*512 = 294912  (16B-aligned)

  k_pre<<<11 + MPART, 256, 0, stream>>>(W, att_src, att_dst, W_edge, att_edge, ea,
                                        ws_, wd_, we_, counts, (float4*)easum_p);
  k_scan<<<NEDGES/256 + 1, 256, 0, stream>>>(ei, ea, we_, counts, slist, aed,
                                             easum_p, easum);
  k_attn<<<NOUT, 512, 0, stream>>>(x, ws_, wd_, we_, easum, counts, slist, aed, z);
  k_gemm1<<<dim3(NOUT/8, 4), 256, 0, stream>>>(z, W, bias, h2);
  k_gemm2<<<dim3(NOUT/8, 4), 256, 0, stream>>>(h2, fcW, fcb, out);
}